// Round 14
// baseline (225.589 us; speedup 1.0000x reference)
//
#include <hip/hip_runtime.h>
#include <cstdint>
#include <cstddef>

typedef unsigned long long ull;

#define KTOP   1000
#define CAP    4096      // candidate gather capacity per (b,c)
#define HBITS  14
#define HB     (1 << HBITS)          // 16384 histogram bins (top-14 float bits)
#define HSHIFT (32 - HBITS)
#define ROWS   1024      // padded rank capacity (>= KTOP)
#define WORDS  16        // 1024 / 64 bitmask words per row
#define HCHUNK 16        // score chunks per (b,c) for the LDS histogram kernel
#define RPW    8         // reduce_pack waves (=bc) per block
#define TPW    (WORDS * 66)   // transposed LDS slice per wave (row-padded x66)

// ---------------- Kernel 1: softmax + SSD decode + hist zeroing ----------------
__global__ void decode_kernel(const float* __restrict__ loc,
                              const float* __restrict__ conf,
                              const float* __restrict__ prior,
                              float* __restrict__ scores,   // [B*Cfg][P]
                              float* __restrict__ cs,       // [B][P][4] center-size
                              unsigned* __restrict__ histz, // hist+cnt region to zero
                              int histW,
                              int B, int C, int P) {
#pragma clang fp contract(off)
    int t = blockIdx.x * blockDim.x + threadIdx.x;

    // zero the hist+cnt region (replaces a hipMemsetAsync dispatch)
    for (int i = t; i < histW; i += gridDim.x * blockDim.x) histz[i] = 0u;

    if (t >= B * P) return;
    int b = t / P;
    int p = t - b * P;

    // softmax over class dim (C small)
    float x[8];
    float m = -INFINITY;
    for (int c = 0; c < C; ++c) {
        x[c] = conf[((size_t)b * C + c) * P + p];
        m = fmaxf(m, x[c]);
    }
    float sum = 0.f;
    for (int c = 0; c < C; ++c) {
        x[c] = expf(x[c] - m);
        sum += x[c];
    }
    for (int c = 1; c < C; ++c) {
        float v = x[c] / sum;
        int bc = b * (C - 1) + (c - 1);
        scores[(size_t)bc * P + p] = v;
    }

    // decode
    float l0 = loc[((size_t)b * 4 + 0) * P + p];
    float l1 = loc[((size_t)b * 4 + 1) * P + p];
    float l2 = loc[((size_t)b * 4 + 2) * P + p];
    float l3 = loc[((size_t)b * 4 + 3) * P + p];
    float4 pr4 = *(const float4*)(prior + (size_t)p * 4);

    float cx = pr4.x + (l0 * 0.1f) * pr4.z;
    float cy = pr4.y + (l1 * 0.1f) * pr4.w;
    float w  = pr4.z * expf(l2 * 0.2f);
    float h  = pr4.w * expf(l3 * 0.2f);

    *(float4*)(cs + ((size_t)b * P + p) * 4) = make_float4(cx, cy, w, h);
}

// ---------------- Kernel 1b: LDS-privatized score histogram ----------------
__global__ void __launch_bounds__(256)
hist_kernel(const float* __restrict__ scores,
            const float* __restrict__ cthp,
            unsigned* __restrict__ hist,     // [NBC][HB]
            int P) {
    __shared__ unsigned sh[HB / 2];          // 32 KB (16-bit packed counters)
    int bc  = blockIdx.x;
    int tid = threadIdx.x;
    float cth = *cthp;

    for (int i = tid; i < HB / 2; i += 256) sh[i] = 0u;
    __syncthreads();

    int chunk = (P + HCHUNK - 1) / HCHUNK;
    int lo = blockIdx.y * chunk;
    int hi = lo + chunk; if (hi > P) hi = P;
    const float* s = scores + (size_t)bc * P;
    for (int p = lo + tid; p < hi; p += 256) {
        float v = s[p];
        if (v >= cth) {
            unsigned bin = __float_as_uint(v) >> HSHIFT;
            atomicAdd(&sh[bin >> 1], (bin & 1u) ? 65536u : 1u);
        }
    }
    __syncthreads();

    unsigned* h = hist + (size_t)bc * HB;
    for (int i = tid; i < HB / 2; i += 256) {
        unsigned v = sh[i];
        if (v & 0xFFFFu)  atomicAdd(&h[2 * i],     v & 0xFFFFu);
        if (v >> 16)      atomicAdd(&h[2 * i + 1], v >> 16);
    }
}

// ---------------- Kernel 2: per-(b,c) pivot bin via parallel suffix scan ----------------
__global__ void __launch_bounds__(256)
pivot_kernel(const unsigned* __restrict__ hist, unsigned* __restrict__ pivot) {
    int bc  = blockIdx.x;
    int t   = threadIdx.x;
    const unsigned* h = hist + (size_t)bc * HB;
    __shared__ unsigned T[256];

    const int per = HB / 256;                // 64 bins per thread
    int base = t * per;
    unsigned S = 0;
    for (int i = 0; i < per; ++i) S += h[base + i];
    T[t] = S;
    __syncthreads();

    for (int d = 1; d < 256; d <<= 1) {
        unsigned add = (t + d < 256) ? T[t + d] : 0u;
        __syncthreads();
        T[t] += add;
        __syncthreads();
    }

    unsigned Tt = T[t];
    unsigned Tn = (t + 1 < 256) ? T[t + 1] : 0u;
    if (Tt >= (unsigned)KTOP && Tn < (unsigned)KTOP) {
        unsigned cum = Tn;
        for (int i = per - 1; i >= 0; --i) {
            cum += h[base + i];
            if (cum >= (unsigned)KTOP) { pivot[bc] = (unsigned)(base + i); break; }
        }
    }
    if (t == 0 && T[0] < (unsigned)KTOP) pivot[bc] = 0u;   // fewer than KTOP valid: take all
}

// ---------------- Kernel 3: gather with BLOCK-aggregated allocation ----------------
__global__ void __launch_bounds__(256)
gather_kernel(const float* __restrict__ scores,
              const unsigned* __restrict__ pivot,
              unsigned* __restrict__ cnt,
              ull* __restrict__ cand,
              const float* __restrict__ cthp, int P) {
    __shared__ unsigned wsum[4];
    __shared__ unsigned s_base;
    int bc = blockIdx.x;
    const float* s = scores + (size_t)bc * P;
    float cth = *cthp;
    unsigned pv = pivot[bc];
    int nchunk = gridDim.y;
    int chunk = (P + nchunk - 1) / nchunk;
    int lo = blockIdx.y * chunk;
    int hi = lo + chunk; if (hi > P) hi = P;
    int tid  = threadIdx.x;
    int lane = tid & 63;
    int wid  = tid >> 6;

    // phase 1: count
    unsigned mycnt = 0;
    for (int p = lo + tid; p < hi; p += 256) {
        float v = s[p];
        unsigned k = __float_as_uint(v);
        if (v >= cth && (k >> HSHIFT) >= pv) ++mycnt;
    }
    unsigned x = mycnt;
    for (int d = 1; d < 64; d <<= 1) {
        unsigned y = (unsigned)__shfl_up((int)x, d);
        if (lane >= d) x += y;
    }
    if (lane == 63) wsum[wid] = x;
    __syncthreads();
    if (tid == 0) {
        unsigned tot = 0;
        for (int w = 0; w < 4; ++w) { unsigned t2 = wsum[w]; wsum[w] = tot; tot += t2; }
        s_base = tot ? atomicAdd(&cnt[bc], tot) : 0u;
    }
    __syncthreads();
    unsigned off = s_base + wsum[wid] + (x - mycnt);

    // phase 2: write (chunk is L2-hot from phase 1)
    ull* cb = cand + (size_t)bc * CAP;
    for (int p = lo + tid; p < hi; p += 256) {
        float v = s[p];
        unsigned k = __float_as_uint(v);
        if (v >= cth && (k >> HSHIFT) >= pv) {
            if (off < CAP)
                cb[off] = ((ull)k << 32) | (unsigned)(~(unsigned)p);
            ++off;
        }
    }
}

// ---------------- Kernel 4: per-(b,c) bitonic sort + export sorted boxes ----------------
__global__ void __launch_bounds__(1024)
sort_kernel(const ull* __restrict__ cand,
            const unsigned* __restrict__ cnt,
            const float* __restrict__ cs,
            float* __restrict__ rows,      // [NBC][KTOP][5] score,cx,cy,w,h
            float4* __restrict__ pbox,     // [NBC][ROWS] point-form x1,y1,x2,y2
            float* __restrict__ bar,       // [NBC][ROWS] area
            int* __restrict__ nselArr,
            int P, int Cfg) {
#pragma clang fp contract(off)
    int bc  = blockIdx.x;
    int b   = bc / Cfg;
    int tid = threadIdx.x;
    __shared__ ull sbuf[CAP];

    int M = (int)cnt[bc]; if (M > CAP) M = CAP;
    int nsel = M < KTOP ? M : KTOP;
    if (tid == 0) nselArr[bc] = nsel;

    int n = 1024;
    while (n < M) n <<= 1;
    for (int i = tid; i < n; i += 1024)
        sbuf[i] = (i < M) ? cand[(size_t)bc * CAP + i] : 0ull;
    __syncthreads();

    for (unsigned k = 2; k <= (unsigned)n; k <<= 1) {
        for (unsigned j = k >> 1; j > 0; j >>= 1) {
            for (unsigned i = tid; i < (unsigned)n; i += 1024) {
                unsigned ixj = i ^ j;
                if (ixj > i) {
                    bool up = ((i & k) == 0u);
                    ull a = sbuf[i], bb = sbuf[ixj];
                    if ((a > bb) == up) { sbuf[i] = bb; sbuf[ixj] = a; }
                }
            }
            __syncthreads();
        }
    }

    for (int r = tid; r < nsel; r += 1024) {
        ull e = sbuf[n - 1 - r];
        float sc = __uint_as_float((unsigned)(e >> 32));
        int idx = (int)(~(unsigned)e);
        const float* c4 = cs + ((size_t)b * P + idx) * 4;
        float cx = c4[0], cy = c4[1], w = c4[2], h = c4[3];
        float x1 = cx - w / 2.f, y1 = cy - h / 2.f;
        float x2 = cx + w / 2.f, y2 = cy + h / 2.f;
        size_t sb = (size_t)bc * ROWS + r;
        pbox[sb] = make_float4(x1, y1, x2, y2);
        bar[sb]  = fmaxf(x2 - x1, 0.f) * fmaxf(y2 - y1, 0.f);
        float* rr = rows + ((size_t)bc * KTOP + r) * 5;
        rr[0] = sc; rr[1] = cx; rr[2] = cy; rr[3] = w; rr[4] = h;
    }
}

// ---------------- Kernel 5: suppression bitmask via per-lane-j + ballot ----------------
__global__ void __launch_bounds__(1024)
mask_kernel(const float4* __restrict__ pbox,
            const float* __restrict__ bar,
            const int* __restrict__ nselArr,
            const float* __restrict__ nthp,
            ull* __restrict__ mask) {       // [NBC][ROWS][WORDS]
#pragma clang fp contract(off)
    int bc   = blockIdx.x;
    int tile = blockIdx.y;                  // 16 tiles x 64 rows
    int tid  = threadIdx.x;
    int nsel = nselArr[bc];
    float nth = *nthp;

    __shared__ float4 sbox[ROWS];           // 16 KB
    __shared__ float  sar[ROWS];            // 4 KB
    size_t sb = (size_t)bc * ROWS;
    sbox[tid] = pbox[sb + tid];
    sar[tid]  = bar[sb + tid];
    __syncthreads();

    int wv   = tid >> 6;                    // wave 0..15
    int lane = tid & 63;
    int i0   = tile * 64 + (wv << 2);       // 4 rows per wave

    float4 bi[4]; float ai[4];
    #pragma unroll
    for (int r = 0; r < 4; ++r) { bi[r] = sbox[i0 + r]; ai[r] = sar[i0 + r]; }   // broadcast

    ull rowbits[4] = {0ull, 0ull, 0ull, 0ull};
    for (int w = 0; w < WORDS; ++w) {
        int j = (w << 6) + lane;
        float4 bj = sbox[j];
        float  aj = sar[j];
        #pragma unroll
        for (int r = 0; r < 4; ++r) {
            int i = i0 + r;
            float ww = fmaxf(fminf(bi[r].z, bj.z) - fmaxf(bi[r].x, bj.x), 0.f);
            float hh = fmaxf(fminf(bi[r].w, bj.w) - fmaxf(bi[r].y, bj.y), 0.f);
            float inter = ww * hh;
            float uni = ai[r] + aj - inter;
            float iou = inter / fmaxf(uni, 1e-12f);
            bool ok = (j > i) && (j < nsel) && (iou > nth);
            ull bits = __ballot(ok);
            if (lane == w) rowbits[r] = bits;
        }
    }
    #pragma unroll
    for (int r = 0; r < 4; ++r)
        if (lane < WORDS)
            mask[(((size_t)bc * ROWS + (i0 + r)) << 4) + lane] = rowbits[r];
}

// ---------------- Kernel 6: wave-per-bc serial reduce + pack (transposed LDS) ----------------
// 8 waves/block, wave <-> (b,c); each wave owns an 8.25 KB transposed LDS
// slice smT[word][row] (row-padded x66). Diag words for chunk c are 64
// CONSECUTIVE ull -> LLVM merges adjacent ds_reads into b128 and batches
// them ahead of the VALU chain (the strided layout prevented this, R13).
// 2 waves/SIMD co-hide residual LDS latency. No __syncthreads anywhere.
__device__ __forceinline__ void nms_chunk_body(
    int c, int nchunk, int lane, int g, int w,
    const ull* __restrict__ mrow, ull* sm,
    ull (&st)[16], ull& S)
{
    // stage chunk c (held in st) into transposed LDS: word (lane&15), row k*4+(lane>>4)
    #pragma unroll
    for (int k = 0; k < 16; ++k)
        sm[w * 66 + (k << 2) + g] = st[k];

    // prefetch chunk c+2 into the freed regs (global, off the serial path)
    if (c + 2 < nchunk) {
        #pragma unroll
        for (int k = 0; k < 16; ++k)
            st[k] = mrow[(size_t)(c + 2) * 1024 + k * 64 + lane];
    }

    // ---- serial greedy on word c: 64 CONSECUTIVE broadcast reads ----
    ull cur = __shfl(S, c);
    const ull* diag = sm + c * 66;
    #pragma unroll
    for (int i = 0; i < 64; ++i) {
        ull di   = diag[i];
        ull supm = (ull)((long long)(cur << (63 - i)) >> 63);  // all-ones iff rank i suppressed
        cur |= di & ~supm;
    }
    ull kbits = ~cur;                        // kept = not suppressed

    // ---- bulk apply: lane (g,w) ORs kept rows g*16..+15 of word w (consecutive) ----
    unsigned sub = (unsigned)((kbits >> (g << 4)) & 0xFFFFull);
    const ull* colw = sm + w * 66 + (g << 4);
    ull part = 0ull;
    #pragma unroll
    for (int i = 0; i < 16; ++i) {
        ull v = colw[i];
        part |= v & (ull)(0ll - (long long)((sub >> i) & 1u));
    }
    part |= __shfl_xor(part, 16);
    part |= __shfl_xor(part, 32);
    S |= part;                               // lanes 0..15 meaningful
    if (lane == c) S = cur;                  // finalize word c
}

__global__ void __launch_bounds__(RPW * 64)
reduce_pack_kernel(const ull* __restrict__ mask,
                   const int* __restrict__ nselArr,
                   const float* __restrict__ rows,
                   float* __restrict__ out, int NBC) {
    __shared__ ull smT[RPW * TPW];           // 8 x 8.25 KB = 66 KB
    int wv   = threadIdx.x >> 6;
    int lane = threadIdx.x & 63;
    int bc   = blockIdx.x * RPW + wv;
    if (bc >= NBC) return;
    ull* sm = smT + wv * TPW;
    int nsel = nselArr[bc];
    const ull* mrow = mask + ((size_t)bc * ROWS << 4);

    int nchunk = (nsel + 63) >> 6;           // <= 16
    ull S = 0ull;                            // lane w<16 holds suppressed-word w
    int g = lane >> 4;
    int w = lane & 15;

    ull ra[16], rb[16];
    if (nchunk > 0) {
        #pragma unroll
        for (int k = 0; k < 16; ++k) ra[k] = mrow[k * 64 + lane];              // chunk 0
        if (nchunk > 1) {
            #pragma unroll
            for (int k = 0; k < 16; ++k) rb[k] = mrow[1024 + k * 64 + lane];   // chunk 1
        }
        #pragma unroll 1
        for (int cc = 0; cc < 8; ++cc) {
            int c0 = cc << 1;
            if (c0 >= nchunk) break;
            nms_chunk_body(c0, nchunk, lane, g, w, mrow, sm, ra, S);
            int c1 = c0 + 1;
            if (c1 >= nchunk) break;
            nms_chunk_body(c1, nchunk, lane, g, w, mrow, sm, rb, S);
        }
    }

    // ---- kept bitmap (lane<16 holds word), wave scan for positions ----
    ull K = 0ull;
    int cnt = 0;
    if (lane < WORDS) {
        int base_i = lane << 6;
        int rem = nsel - base_i;
        ull valid = 0ull;
        if (rem > 0) valid = (rem >= 64) ? ~0ull : ((1ull << rem) - 1ull);
        K = (~S) & valid;
        cnt = __popcll(K);
    }
    int x = cnt;
    for (int d = 1; d < 64; d <<= 1) {
        int y = __shfl_up(x, d);
        if (lane >= d) x += y;
    }
    int pref = x - cnt;                       // exclusive prefix (valid for lane<16)
    int tot  = __shfl(x, 63);                 // total kept

    const float* rbase = rows + (size_t)bc * KTOP * 5;
    float* obase = out + (size_t)bc * KTOP * 5;
    #pragma unroll 1
    for (int it = 0; it < WORDS; ++it) {
        int r = (it << 6) + lane;
        if (r >= KTOP) break;                 // only trims tail lanes of it=15
        ull kwv   = (ull)__shfl((long long)K, it);
        int prefw = __shfl(pref, it);
        if ((kwv >> lane) & 1ull) {
            int pos = prefw + __popcll(kwv & ((1ull << lane) - 1ull));
            const float* rr = rbase + r * 5;
            float* oo = obase + pos * 5;
            oo[0] = rr[0]; oo[1] = rr[1]; oo[2] = rr[2]; oo[3] = rr[3]; oo[4] = rr[4];
        }
        if (r >= tot) {                       // zero-fill tail (replaces out memset)
            float* oo = obase + r * 5;
            oo[0] = 0.f; oo[1] = 0.f; oo[2] = 0.f; oo[3] = 0.f; oo[4] = 0.f;
        }
    }
}

// ------------------------------- launcher -------------------------------
extern "C" void kernel_launch(void* const* d_in, const int* in_sizes, int n_in,
                              void* d_out, int out_size, void* d_ws, size_t ws_size,
                              hipStream_t stream) {
    (void)n_in; (void)out_size; (void)ws_size;
    const float* loc   = (const float*)d_in[0];
    const float* conf  = (const float*)d_in[1];
    const float* prior = (const float*)d_in[2];
    const float* cth   = (const float*)d_in[3];
    const float* nth   = (const float*)d_in[4];
    float* out = (float*)d_out;

    int P   = in_sizes[2] / 4;
    int B   = in_sizes[0] / (4 * P);
    int C   = in_sizes[1] / (B * P);
    int Cfg = C - 1;
    int NBC = B * Cfg;

    // ---- carve workspace (256B aligned sections; widest types first) ----
    char* base = (char*)d_ws;
    size_t off = 0;
    auto carve = [&](size_t bytes) { char* p = base + off; off = (off + bytes + 255) & ~(size_t)255; return p; };

    float4*   pbox   = (float4*)  carve((size_t)NBC * ROWS * 16);
    ull*      cand   = (ull*)     carve((size_t)NBC * CAP * 8);
    ull*      mask   = (ull*)     carve((size_t)NBC * ROWS * WORDS * 8);
    float*    scores = (float*)   carve((size_t)NBC * P * 4);
    float*    cs     = (float*)   carve((size_t)B * P * 4 * 4);
    float*    rows   = (float*)   carve((size_t)NBC * KTOP * 5 * 4);
    float*    bar    = (float*)   carve((size_t)NBC * ROWS * 4);
    unsigned* hist   = (unsigned*)carve((size_t)NBC * HB * 4 + (size_t)NBC * 4);  // hist + cnt contiguous
    unsigned* cnt    = hist + (size_t)NBC * HB;
    unsigned* pivot  = (unsigned*)carve((size_t)NBC * 4);
    int*      nselA  = (int*)     carve((size_t)NBC * 4);

    int histW = NBC * HB + NBC;              // words to zero (hist + cnt)

    int n1 = B * P;
    decode_kernel<<<(n1 + 255) / 256, 256, 0, stream>>>(loc, conf, prior, scores, cs, hist, histW, B, C, P);
    hist_kernel<<<dim3(NBC, HCHUNK), 256, 0, stream>>>(scores, cth, hist, P);
    pivot_kernel<<<NBC, 256, 0, stream>>>(hist, pivot);
    gather_kernel<<<dim3(NBC, 32), 256, 0, stream>>>(scores, pivot, cnt, cand, cth, P);
    sort_kernel<<<NBC, 1024, 0, stream>>>(cand, cnt, cs, rows, pbox, bar, nselA, P, Cfg);
    mask_kernel<<<dim3(NBC, ROWS / 64), 1024, 0, stream>>>(pbox, bar, nselA, nth, mask);
    reduce_pack_kernel<<<(NBC + RPW - 1) / RPW, RPW * 64, 0, stream>>>(mask, nselA, rows, out, NBC);
}

// Round 15
// 217.676 us; speedup vs baseline: 1.0364x; 1.0364x over previous
//
#include <hip/hip_runtime.h>
#include <cstdint>
#include <cstddef>

typedef unsigned long long ull;

#define KTOP   1000
#define CAP    4096      // candidate gather capacity per (b,c)
#define HBITS  14
#define HB     (1 << HBITS)          // 16384 histogram bins (top-14 float bits)
#define HSHIFT (32 - HBITS)
#define ROWS   1024      // padded rank capacity (>= KTOP)
#define WORDS  16        // 1024 / 64 bitmask words per row
#define HCHUNK 16        // score chunks per (b,c) for the LDS histogram kernel

// ---------------- Kernel 1: softmax + SSD decode + hist zeroing ----------------
__global__ void decode_kernel(const float* __restrict__ loc,
                              const float* __restrict__ conf,
                              const float* __restrict__ prior,
                              float* __restrict__ scores,   // [B*Cfg][P]
                              float* __restrict__ cs,       // [B][P][4] center-size
                              unsigned* __restrict__ histz, // hist+cnt region to zero
                              int histW,
                              int B, int C, int P) {
#pragma clang fp contract(off)
    int t = blockIdx.x * blockDim.x + threadIdx.x;

    // zero the hist+cnt region (replaces a hipMemsetAsync dispatch)
    for (int i = t; i < histW; i += gridDim.x * blockDim.x) histz[i] = 0u;

    if (t >= B * P) return;
    int b = t / P;
    int p = t - b * P;

    // softmax over class dim (C small)
    float x[8];
    float m = -INFINITY;
    for (int c = 0; c < C; ++c) {
        x[c] = conf[((size_t)b * C + c) * P + p];
        m = fmaxf(m, x[c]);
    }
    float sum = 0.f;
    for (int c = 0; c < C; ++c) {
        x[c] = expf(x[c] - m);
        sum += x[c];
    }
    for (int c = 1; c < C; ++c) {
        float v = x[c] / sum;
        int bc = b * (C - 1) + (c - 1);
        scores[(size_t)bc * P + p] = v;
    }

    // decode
    float l0 = loc[((size_t)b * 4 + 0) * P + p];
    float l1 = loc[((size_t)b * 4 + 1) * P + p];
    float l2 = loc[((size_t)b * 4 + 2) * P + p];
    float l3 = loc[((size_t)b * 4 + 3) * P + p];
    float4 pr4 = *(const float4*)(prior + (size_t)p * 4);

    float cx = pr4.x + (l0 * 0.1f) * pr4.z;
    float cy = pr4.y + (l1 * 0.1f) * pr4.w;
    float w  = pr4.z * expf(l2 * 0.2f);
    float h  = pr4.w * expf(l3 * 0.2f);

    *(float4*)(cs + ((size_t)b * P + p) * 4) = make_float4(cx, cy, w, h);
}

// ---------------- Kernel 1b: LDS-privatized score histogram ----------------
__global__ void __launch_bounds__(256)
hist_kernel(const float* __restrict__ scores,
            const float* __restrict__ cthp,
            unsigned* __restrict__ hist,     // [NBC][HB]
            int P) {
    __shared__ unsigned sh[HB / 2];          // 32 KB (16-bit packed counters)
    int bc  = blockIdx.x;
    int tid = threadIdx.x;
    float cth = *cthp;

    for (int i = tid; i < HB / 2; i += 256) sh[i] = 0u;
    __syncthreads();

    int chunk = (P + HCHUNK - 1) / HCHUNK;
    int lo = blockIdx.y * chunk;
    int hi = lo + chunk; if (hi > P) hi = P;
    const float* s = scores + (size_t)bc * P;
    for (int p = lo + tid; p < hi; p += 256) {
        float v = s[p];
        if (v >= cth) {
            unsigned bin = __float_as_uint(v) >> HSHIFT;
            atomicAdd(&sh[bin >> 1], (bin & 1u) ? 65536u : 1u);
        }
    }
    __syncthreads();

    unsigned* h = hist + (size_t)bc * HB;
    for (int i = tid; i < HB / 2; i += 256) {
        unsigned v = sh[i];
        if (v & 0xFFFFu)  atomicAdd(&h[2 * i],     v & 0xFFFFu);
        if (v >> 16)      atomicAdd(&h[2 * i + 1], v >> 16);
    }
}

// ---------------- Kernel 2: per-(b,c) pivot bin via parallel suffix scan ----------------
__global__ void __launch_bounds__(256)
pivot_kernel(const unsigned* __restrict__ hist, unsigned* __restrict__ pivot) {
    int bc  = blockIdx.x;
    int t   = threadIdx.x;
    const unsigned* h = hist + (size_t)bc * HB;
    __shared__ unsigned T[256];

    const int per = HB / 256;                // 64 bins per thread
    int base = t * per;
    unsigned S = 0;
    for (int i = 0; i < per; ++i) S += h[base + i];
    T[t] = S;
    __syncthreads();

    for (int d = 1; d < 256; d <<= 1) {
        unsigned add = (t + d < 256) ? T[t + d] : 0u;
        __syncthreads();
        T[t] += add;
        __syncthreads();
    }

    unsigned Tt = T[t];
    unsigned Tn = (t + 1 < 256) ? T[t + 1] : 0u;
    if (Tt >= (unsigned)KTOP && Tn < (unsigned)KTOP) {
        unsigned cum = Tn;
        for (int i = per - 1; i >= 0; --i) {
            cum += h[base + i];
            if (cum >= (unsigned)KTOP) { pivot[bc] = (unsigned)(base + i); break; }
        }
    }
    if (t == 0 && T[0] < (unsigned)KTOP) pivot[bc] = 0u;   // fewer than KTOP valid: take all
}

// ---------------- Kernel 3: gather with BLOCK-aggregated allocation ----------------
__global__ void __launch_bounds__(256)
gather_kernel(const float* __restrict__ scores,
              const unsigned* __restrict__ pivot,
              unsigned* __restrict__ cnt,
              ull* __restrict__ cand,
              const float* __restrict__ cthp, int P) {
    __shared__ unsigned wsum[4];
    __shared__ unsigned s_base;
    int bc = blockIdx.x;
    const float* s = scores + (size_t)bc * P;
    float cth = *cthp;
    unsigned pv = pivot[bc];
    int nchunk = gridDim.y;
    int chunk = (P + nchunk - 1) / nchunk;
    int lo = blockIdx.y * chunk;
    int hi = lo + chunk; if (hi > P) hi = P;
    int tid  = threadIdx.x;
    int lane = tid & 63;
    int wid  = tid >> 6;

    // phase 1: count
    unsigned mycnt = 0;
    for (int p = lo + tid; p < hi; p += 256) {
        float v = s[p];
        unsigned k = __float_as_uint(v);
        if (v >= cth && (k >> HSHIFT) >= pv) ++mycnt;
    }
    unsigned x = mycnt;
    for (int d = 1; d < 64; d <<= 1) {
        unsigned y = (unsigned)__shfl_up((int)x, d);
        if (lane >= d) x += y;
    }
    if (lane == 63) wsum[wid] = x;
    __syncthreads();
    if (tid == 0) {
        unsigned tot = 0;
        for (int w = 0; w < 4; ++w) { unsigned t2 = wsum[w]; wsum[w] = tot; tot += t2; }
        s_base = tot ? atomicAdd(&cnt[bc], tot) : 0u;
    }
    __syncthreads();
    unsigned off = s_base + wsum[wid] + (x - mycnt);

    // phase 2: write (chunk is L2-hot from phase 1)
    ull* cb = cand + (size_t)bc * CAP;
    for (int p = lo + tid; p < hi; p += 256) {
        float v = s[p];
        unsigned k = __float_as_uint(v);
        if (v >= cth && (k >> HSHIFT) >= pv) {
            if (off < CAP)
                cb[off] = ((ull)k << 32) | (unsigned)(~(unsigned)p);
            ++off;
        }
    }
}

// ---------------- Kernel 4: per-(b,c) bitonic sort + export sorted boxes ----------------
__global__ void __launch_bounds__(1024)
sort_kernel(const ull* __restrict__ cand,
            const unsigned* __restrict__ cnt,
            const float* __restrict__ cs,
            float* __restrict__ rows,      // [NBC][KTOP][5] score,cx,cy,w,h
            float4* __restrict__ pbox,     // [NBC][ROWS] point-form x1,y1,x2,y2
            float* __restrict__ bar,       // [NBC][ROWS] area
            int* __restrict__ nselArr,
            int P, int Cfg) {
#pragma clang fp contract(off)
    int bc  = blockIdx.x;
    int b   = bc / Cfg;
    int tid = threadIdx.x;
    __shared__ ull sbuf[CAP];

    int M = (int)cnt[bc]; if (M > CAP) M = CAP;
    int nsel = M < KTOP ? M : KTOP;
    if (tid == 0) nselArr[bc] = nsel;

    int n = 1024;
    while (n < M) n <<= 1;
    for (int i = tid; i < n; i += 1024)
        sbuf[i] = (i < M) ? cand[(size_t)bc * CAP + i] : 0ull;
    __syncthreads();

    for (unsigned k = 2; k <= (unsigned)n; k <<= 1) {
        for (unsigned j = k >> 1; j > 0; j >>= 1) {
            for (unsigned i = tid; i < (unsigned)n; i += 1024) {
                unsigned ixj = i ^ j;
                if (ixj > i) {
                    bool up = ((i & k) == 0u);
                    ull a = sbuf[i], bb = sbuf[ixj];
                    if ((a > bb) == up) { sbuf[i] = bb; sbuf[ixj] = a; }
                }
            }
            __syncthreads();
        }
    }

    for (int r = tid; r < nsel; r += 1024) {
        ull e = sbuf[n - 1 - r];
        float sc = __uint_as_float((unsigned)(e >> 32));
        int idx = (int)(~(unsigned)e);
        const float* c4 = cs + ((size_t)b * P + idx) * 4;
        float cx = c4[0], cy = c4[1], w = c4[2], h = c4[3];
        float x1 = cx - w / 2.f, y1 = cy - h / 2.f;
        float x2 = cx + w / 2.f, y2 = cy + h / 2.f;
        size_t sb = (size_t)bc * ROWS + r;
        pbox[sb] = make_float4(x1, y1, x2, y2);
        bar[sb]  = fmaxf(x2 - x1, 0.f) * fmaxf(y2 - y1, 0.f);
        float* rr = rows + ((size_t)bc * KTOP + r) * 5;
        rr[0] = sc; rr[1] = cx; rr[2] = cy; rr[3] = w; rr[4] = h;
    }
}

// ---------------- Kernel 5: suppression bitmask via per-lane-j + ballot ----------------
__global__ void __launch_bounds__(1024)
mask_kernel(const float4* __restrict__ pbox,
            const float* __restrict__ bar,
            const int* __restrict__ nselArr,
            const float* __restrict__ nthp,
            ull* __restrict__ mask) {       // [NBC][ROWS][WORDS]
#pragma clang fp contract(off)
    int bc   = blockIdx.x;
    int tile = blockIdx.y;                  // 16 tiles x 64 rows
    int tid  = threadIdx.x;
    int nsel = nselArr[bc];
    float nth = *nthp;

    __shared__ float4 sbox[ROWS];           // 16 KB
    __shared__ float  sar[ROWS];            // 4 KB
    size_t sb = (size_t)bc * ROWS;
    sbox[tid] = pbox[sb + tid];
    sar[tid]  = bar[sb + tid];
    __syncthreads();

    int wv   = tid >> 6;                    // wave 0..15
    int lane = tid & 63;
    int i0   = tile * 64 + (wv << 2);       // 4 rows per wave

    float4 bi[4]; float ai[4];
    #pragma unroll
    for (int r = 0; r < 4; ++r) { bi[r] = sbox[i0 + r]; ai[r] = sar[i0 + r]; }   // broadcast

    ull rowbits[4] = {0ull, 0ull, 0ull, 0ull};
    for (int w = 0; w < WORDS; ++w) {
        int j = (w << 6) + lane;
        float4 bj = sbox[j];
        float  aj = sar[j];
        #pragma unroll
        for (int r = 0; r < 4; ++r) {
            int i = i0 + r;
            float ww = fmaxf(fminf(bi[r].z, bj.z) - fmaxf(bi[r].x, bj.x), 0.f);
            float hh = fmaxf(fminf(bi[r].w, bj.w) - fmaxf(bi[r].y, bj.y), 0.f);
            float inter = ww * hh;
            float uni = ai[r] + aj - inter;
            float iou = inter / fmaxf(uni, 1e-12f);
            bool ok = (j > i) && (j < nsel) && (iou > nth);
            ull bits = __ballot(ok);
            if (lane == w) rowbits[r] = bits;
        }
    }
    #pragma unroll
    for (int r = 0; r < 4; ++r)
        if (lane < WORDS)
            mask[(((size_t)bc * ROWS + (i0 + r)) << 4) + lane] = rowbits[r];
}

// ---------------- Kernel 6: fused serial reduce (SALU chain) + parallel pack ----------------
// The serial greedy recurrence is wave-uniform, so it is computed on the
// SCALAR unit: S and the diagonal words are pulled into SGPRs via readlane
// (diag of row r = reg pr[r>>2], lane (r&3)*16+c — straight from the global
// prefetch registers, no LDS in the chain). SALU dep latency ~1-2 cyc vs
// ~4+ for VALU 64-bit ops — the chain drops from ~25k to ~8k cycles.
__device__ __forceinline__ ull readlane_u64(ull v, int srclane) {
    unsigned lo = (unsigned)__builtin_amdgcn_readlane((int)(unsigned)(v & 0xFFFFFFFFull), srclane);
    unsigned hi = (unsigned)__builtin_amdgcn_readlane((int)(unsigned)(v >> 32), srclane);
    return ((ull)hi << 32) | lo;
}

__device__ __forceinline__ void nms_chunk_body(
    int c, int nchunk, int lane, int g, int w,
    const ull* __restrict__ mrow, ull* sm,
    ull (&pr)[16], ull (&st)[16], ull& S)
{
    int cb = (c & 1) << 10;
    int nb = ((c + 1) & 1) << 10;

    // ---- serial greedy on word c: uniform SALU chain, diag via readlane ----
    // pr holds chunk c's data at entry: pr[k] = chunk-linear element k*64+lane,
    // so diag of row r (elem r*16+c) lives in pr[r>>2] at lane (r&3)*16+c.
    ull cur = readlane_u64(S, c);
    #pragma unroll
    for (int r = 0; r < 64; ++r) {
        ull d = readlane_u64(pr[r >> 2], ((r & 3) << 4) + c);   // off-chain, uniform
        cur |= d & (((cur >> r) & 1ull) - 1ull);                // SALU: kept -> OR in row r
    }
    ull kbits = ~cur;                        // kept = not suppressed (uniform)

    // ---- prefetch chunk c+2 into pr (regs free after the readlanes) ----
    if (c + 2 < nchunk) {
        #pragma unroll
        for (int k = 0; k < 16; ++k)
            pr[k] = mrow[(size_t)(c + 2) * 1024 + k * 64 + lane];
    }

    // ---- bulk apply: lane (g,w) ORs kept rows of group g, word w ----
    unsigned sub = (unsigned)((kbits >> (g << 4)) & 0xFFFFull);
    int rbase2 = cb + (g << 8) + w;
    ull part = 0ull;
    #pragma unroll
    for (int i = 0; i < 16; ++i) {
        ull v = sm[rbase2 + (i << 4)];       // unconditional, pipelined
        part |= v & (ull)(0ll - (long long)((sub >> i) & 1u));
    }
    part |= __shfl_xor(part, 16);
    part |= __shfl_xor(part, 32);
    S |= part;                               // lanes 0..15 meaningful
    if (lane == c) S = cur;                  // finalize word c

    if (c + 1 < nchunk) {                    // stage chunk c+1 into the other LDS buffer
        #pragma unroll
        for (int k = 0; k < 16; ++k) sm[nb + k * 64 + lane] = st[k];
    }
}

__global__ void __launch_bounds__(256)
reduce_pack_kernel(const ull* __restrict__ mask,
                   const int* __restrict__ nselArr,
                   const float* __restrict__ rows,
                   float* __restrict__ out) {
    int bc  = blockIdx.x;
    int tid = threadIdx.x;
    int nsel = nselArr[bc];
    const ull* mrow = mask + ((size_t)bc * ROWS << 4);

    __shared__ ull sm[2048];                // 2 x (64 rows x 16 words) = 16 KB
    __shared__ ull kw[WORDS];
    __shared__ unsigned pref[WORDS + 1];

    if (tid < 64) {                          // wave 0: serial reduce
        int lane = tid;
        int nchunk = (nsel + 63) >> 6;       // <= 16
        ull S = 0ull;
        int g = lane >> 4;
        int w = lane & 15;

        ull ra[16], rb[16];
        if (nchunk > 0) {
            #pragma unroll
            for (int k = 0; k < 16; ++k) ra[k] = mrow[k * 64 + lane];              // chunk 0
            if (nchunk > 1) {
                #pragma unroll
                for (int k = 0; k < 16; ++k) rb[k] = mrow[1024 + k * 64 + lane];   // chunk 1
            }
            #pragma unroll
            for (int k = 0; k < 16; ++k) sm[k * 64 + lane] = ra[k];                // stage chunk 0

            #pragma unroll 1
            for (int cc = 0; cc < 8; ++cc) {
                int c0 = cc << 1;
                if (c0 >= nchunk) break;
                nms_chunk_body(c0, nchunk, lane, g, w, mrow, sm, ra, rb, S);
                int c1 = c0 + 1;
                if (c1 >= nchunk) break;
                nms_chunk_body(c1, nchunk, lane, g, w, mrow, sm, rb, ra, S);
            }
        }

        if (lane < WORDS) {
            int base_i = lane << 6;
            ull valid = 0ull;
            int rem = nsel - base_i;
            if (rem > 0) valid = (rem >= 64) ? ~0ull : ((1ull << rem) - 1ull);
            kw[lane] = (~S) & valid;
        }
    }
    __syncthreads();

    if (tid == 0) {
        unsigned c = 0;
        for (int w = 0; w < WORDS; ++w) { pref[w] = c; c += (unsigned)__popcll(kw[w]); }
        pref[WORDS] = c;
    }
    __syncthreads();
    unsigned tot = pref[WORDS];

    const float* rbase = rows + (size_t)bc * KTOP * 5;
    float* obase = out + (size_t)bc * KTOP * 5;
    for (int r = tid; r < KTOP; r += 256) {
        ull wv = kw[r >> 6];
        if ((wv >> (r & 63)) & 1ull) {
            int pos = (int)pref[r >> 6] + __popcll(wv & ((1ull << (r & 63)) - 1ull));
            const float* rr = rbase + r * 5;
            float* oo = obase + pos * 5;
            oo[0] = rr[0]; oo[1] = rr[1]; oo[2] = rr[2]; oo[3] = rr[3]; oo[4] = rr[4];
        }
        if (r >= (int)tot) {                 // zero-fill tail (replaces out memset)
            float* oo = obase + r * 5;
            oo[0] = 0.f; oo[1] = 0.f; oo[2] = 0.f; oo[3] = 0.f; oo[4] = 0.f;
        }
    }
}

// ------------------------------- launcher -------------------------------
extern "C" void kernel_launch(void* const* d_in, const int* in_sizes, int n_in,
                              void* d_out, int out_size, void* d_ws, size_t ws_size,
                              hipStream_t stream) {
    (void)n_in; (void)out_size; (void)ws_size;
    const float* loc   = (const float*)d_in[0];
    const float* conf  = (const float*)d_in[1];
    const float* prior = (const float*)d_in[2];
    const float* cth   = (const float*)d_in[3];
    const float* nth   = (const float*)d_in[4];
    float* out = (float*)d_out;

    int P   = in_sizes[2] / 4;
    int B   = in_sizes[0] / (4 * P);
    int C   = in_sizes[1] / (B * P);
    int Cfg = C - 1;
    int NBC = B * Cfg;

    // ---- carve workspace (256B aligned sections; widest types first) ----
    char* base = (char*)d_ws;
    size_t off = 0;
    auto carve = [&](size_t bytes) { char* p = base + off; off = (off + bytes + 255) & ~(size_t)255; return p; };

    float4*   pbox   = (float4*)  carve((size_t)NBC * ROWS * 16);
    ull*      cand   = (ull*)     carve((size_t)NBC * CAP * 8);
    ull*      mask   = (ull*)     carve((size_t)NBC * ROWS * WORDS * 8);
    float*    scores = (float*)   carve((size_t)NBC * P * 4);
    float*    cs     = (float*)   carve((size_t)B * P * 4 * 4);
    float*    rows   = (float*)   carve((size_t)NBC * KTOP * 5 * 4);
    float*    bar    = (float*)   carve((size_t)NBC * ROWS * 4);
    unsigned* hist   = (unsigned*)carve((size_t)NBC * HB * 4 + (size_t)NBC * 4);  // hist + cnt contiguous
    unsigned* cnt    = hist + (size_t)NBC * HB;
    unsigned* pivot  = (unsigned*)carve((size_t)NBC * 4);
    int*      nselA  = (int*)     carve((size_t)NBC * 4);

    int histW = NBC * HB + NBC;              // words to zero (hist + cnt)

    int n1 = B * P;
    decode_kernel<<<(n1 + 255) / 256, 256, 0, stream>>>(loc, conf, prior, scores, cs, hist, histW, B, C, P);
    hist_kernel<<<dim3(NBC, HCHUNK), 256, 0, stream>>>(scores, cth, hist, P);
    pivot_kernel<<<NBC, 256, 0, stream>>>(hist, pivot);
    gather_kernel<<<dim3(NBC, 32), 256, 0, stream>>>(scores, pivot, cnt, cand, cth, P);
    sort_kernel<<<NBC, 1024, 0, stream>>>(cand, cnt, cs, rows, pbox, bar, nselA, P, Cfg);
    mask_kernel<<<dim3(NBC, ROWS / 64), 1024, 0, stream>>>(pbox, bar, nselA, nth, mask);
    reduce_pack_kernel<<<NBC, 256, 0, stream>>>(mask, nselA, rows, out);
}